// Round 1
// baseline (153.110 us; speedup 1.0000x reference)
//
#include <hip/hip_runtime.h>

#define N_ 4
#define C_ 256
#define H_ 128
#define W_ 128
#define HW_ (H_*W_)
#define BINS 256      // 16x16 pooled positions
#define OC 9
#define EPS_ 1e-5f

// Kernel 1: 8x8 average pool. Block per (n,c), 256 threads, float4 coalesced.
// Writes xp layout [n][bin][c] so stage-2 channel reads are coalesced.
__global__ __launch_bounds__(256) void pool_kernel(const float* __restrict__ x,
                                                   float* __restrict__ xp) {
    int b = blockIdx.x;          // n*C + c
    int n = b >> 8, c = b & 255;
    const float4* xv = (const float4*)(x + (size_t)b * HW_);
    __shared__ float bins[BINS];
    int t = threadIdx.x;
    bins[t] = 0.f;
    __syncthreads();
    int xb = (t & 31) >> 1;      // pooled col bin of this thread's float4
    #pragma unroll
    for (int k = 0; k < 16; ++k) {   // k == pooled row bin
        float4 v = xv[k * 256 + t];  // flat pixel = k*1024 + 4t  (coalesced)
        float s = v.x + v.y + v.z + v.w;
        atomicAdd(&bins[k * 16 + xb], s);
    }
    __syncthreads();
    // bin t -> xp[n][t][c]
    xp[((size_t)n << 16) + (t << 8) + c] = bins[t] * (1.f / 64.f);
}

// Kernel 2: 1x1 conv (9x256 GEMV). One wave per (n,bin).
__global__ __launch_bounds__(64) void conv1x1_kernel(const float* __restrict__ xp,
                                                     const float* __restrict__ wconv,
                                                     float* __restrict__ sraw) {
    int b = blockIdx.x;          // n*BINS + bin
    int t = threadIdx.x;         // 0..63
    const float* xc = xp + ((size_t)b << 8);
    float v[4];
    #pragma unroll
    for (int i = 0; i < 4; ++i) v[i] = xc[i * 64 + t];
    #pragma unroll
    for (int o = 0; o < OC; ++o) {
        float s = 0.f;
        #pragma unroll
        for (int i = 0; i < 4; ++i) s += wconv[o * 256 + i * 64 + t] * v[i];
        #pragma unroll
        for (int off = 32; off > 0; off >>= 1) s += __shfl_down(s, off);
        if (t == 0) sraw[o * (N_ * BINS) + b] = s;   // [o][n*256+bin]
    }
}

// Kernel 3: BatchNorm (training stats, biased var) over 1024 samples per o,
// then scatter normalized taps into w9 layout [n*256+bin][9].
__global__ __launch_bounds__(256) void bn_kernel(const float* __restrict__ sraw,
                                                 const float* __restrict__ gamma,
                                                 const float* __restrict__ beta,
                                                 float* __restrict__ w9) {
    int o = blockIdx.x;
    int t = threadIdx.x;
    const float* src = sraw + o * (N_ * BINS);
    float v[4], sum = 0.f, sq = 0.f;
    #pragma unroll
    for (int i = 0; i < 4; ++i) {
        v[i] = src[i * 256 + t];
        sum += v[i];
        sq += v[i] * v[i];
    }
    __shared__ float ls[8];
    __shared__ float sc[2];
    #pragma unroll
    for (int off = 32; off > 0; off >>= 1) {
        sum += __shfl_down(sum, off);
        sq  += __shfl_down(sq, off);
    }
    int wave = t >> 6;
    if ((t & 63) == 0) { ls[wave] = sum; ls[4 + wave] = sq; }
    __syncthreads();
    if (t == 0) {
        float S = ls[0] + ls[1] + ls[2] + ls[3];
        float Q = ls[4] + ls[5] + ls[6] + ls[7];
        float mu = S * (1.f / 1024.f);
        float var = Q * (1.f / 1024.f) - mu * mu;
        float scale = gamma[o] * rsqrtf(var + EPS_);
        sc[0] = scale;
        sc[1] = beta[o] - mu * scale;
    }
    __syncthreads();
    float scale = sc[0], shift = sc[1];
    #pragma unroll
    for (int i = 0; i < 4; ++i) {
        int idx = i * 256 + t;               // n*256 + bin
        w9[idx * 9 + o] = v[i] * scale + shift;
    }
}

// Kernel 4: depthwise 3x3 conv, per-(n,ch) dynamic 9-tap kernel, zero pad 1.
// Block per (n,ch,row-tile of 16). LDS tile 18 rows x 132 (stride 132 floats
// = 528 B, 16B-aligned per row; col x stored at index x+1; halo cols zeroed).
// Each thread computes a 2-row x 4-col micro-tile.
__global__ __launch_bounds__(256) void dwconv_kernel(const float* __restrict__ x,
                                                     const float* __restrict__ w9,
                                                     float* __restrict__ out) {
    int b = blockIdx.x;
    int plane = b >> 3;          // n*C + ch
    int rt = b & 7;
    int r0 = rt * 16;
    const float* xin = x + (size_t)plane * HW_;
    float* po = out + (size_t)plane * HW_;
    const float* wp = w9 + plane * 9;    // block-uniform address -> s_load
    float w[9];
    #pragma unroll
    for (int i = 0; i < 9; ++i) w[i] = wp[i];

    __shared__ __align__(16) float lds[18 * 132];
    int t = threadIdx.x;
    if (t < 18) {                 // zero halo columns (col -1 and col 128)
        lds[t * 132] = 0.f;
        lds[t * 132 + 129] = 0.f;
    }
    // stage 18 rows x 128 cols = 576 float4 loads, coalesced
    #pragma unroll
    for (int i = 0; i < 3; ++i) {
        int vi = i * 256 + t;
        if (vi < 576) {
            int lr = vi >> 5;            // lds row 0..17
            int c4 = (vi & 31) << 2;     // col 0,4,...,124
            int gr = r0 - 1 + lr;        // global row
            float4 val = make_float4(0.f, 0.f, 0.f, 0.f);
            if (gr >= 0 && gr < H_) val = *(const float4*)&xin[gr * W_ + c4];
            float* d = &lds[lr * 132 + c4 + 1];
            d[0] = val.x; d[1] = val.y; d[2] = val.z; d[3] = val.w;
        }
    }
    __syncthreads();

    int mr = t >> 5;              // 0..7  -> out rows olr, olr+1
    int mc = t & 31;              // 0..31 -> out cols mc*4..mc*4+3
    int olr = mr * 2;
    int oc0 = mc * 4;
    // rowv[j][i] = input col (oc0 + i - 1) of lds row (olr + j)
    float rowv[4][6];
    #pragma unroll
    for (int j = 0; j < 4; ++j) {
        const float* rp = &lds[(olr + j) * 132 + oc0];
        float4 a = *(const float4*)rp;    // 16B-aligned ds_read_b128
        rowv[j][0] = a.x; rowv[j][1] = a.y; rowv[j][2] = a.z; rowv[j][3] = a.w;
        rowv[j][4] = rp[4]; rowv[j][5] = rp[5];
    }
    #pragma unroll
    for (int rr = 0; rr < 2; ++rr) {
        float res[4];
        #pragma unroll
        for (int cc = 0; cc < 4; ++cc) {
            float s = 0.f;
            #pragma unroll
            for (int dy = 0; dy < 3; ++dy)
                #pragma unroll
                for (int dx = 0; dx < 3; ++dx)
                    s += w[dy * 3 + dx] * rowv[rr + dy][cc + dx];
            res[cc] = s;
        }
        *(float4*)&po[(r0 + olr + rr) * W_ + oc0] =
            make_float4(res[0], res[1], res[2], res[3]);
    }
}

extern "C" void kernel_launch(void* const* d_in, const int* in_sizes, int n_in,
                              void* d_out, int out_size, void* d_ws, size_t ws_size,
                              hipStream_t stream) {
    const float* x     = (const float*)d_in[0];
    const float* wconv = (const float*)d_in[1];
    const float* gamma = (const float*)d_in[2];
    const float* beta  = (const float*)d_in[3];
    float* out = (float*)d_out;

    float* xp   = (float*)d_ws;                 // N*BINS*C = 262144 floats
    float* sraw = xp + N_ * BINS * C_;          // OC*N*BINS = 9216 floats
    float* w9   = sraw + OC * N_ * BINS;        // N*BINS*OC = 9216 floats

    pool_kernel   <<<N_ * C_,      256, 0, stream>>>(x, xp);
    conv1x1_kernel<<<N_ * BINS,     64, 0, stream>>>(xp, wconv, sraw);
    bn_kernel     <<<OC,           256, 0, stream>>>(sraw, gamma, beta, w9);
    dwconv_kernel <<<N_ * C_ * 8,  256, 0, stream>>>(x, w9, out);
}